// Round 9
// baseline (822.219 us; speedup 1.0000x reference)
//
#include <hip/hip_runtime.h>

#define NPER 4096
#define MS   1024
#define CIN  64
#define LCAP 384

typedef float  f32x4 __attribute__((ext_vector_type(4)));
typedef short  s16x8 __attribute__((ext_vector_type(8)));
typedef unsigned long long u64;

// Exact d2 matching XLA: sub, rounded squares, left-assoc sum; no fma.
__device__ __forceinline__ float d2_exact(float ax, float ay, float az,
                                          float bx, float by, float bz) {
  float dx = __fsub_rn(ax, bx);
  float dy = __fsub_rn(ay, by);
  float dz = __fsub_rn(az, bz);
  return __fadd_rn(__fadd_rn(__fmul_rn(dx, dx), __fmul_rn(dy, dy)), __fmul_rn(dz, dz));
}

__device__ __forceinline__ unsigned short f2bf(float f) {
  unsigned b = __float_as_uint(f);
  return (unsigned short)((b + 0x7FFFu + ((b >> 16) & 1u)) >> 16);
}

__device__ __forceinline__ u64 mk64(unsigned hi, unsigned lo) {
  return ((u64)hi << 32) | lo;
}

// Exact top-2 merge of two descending pairs (all keys unique):
// new1 = max(a1,o1); new2 = max(min(a1,o1), max(a2,o2)).
__device__ __forceinline__ void top2_merge(u64& a1, u64& a2, u64 o1, u64 o2) {
  bool g = a1 > o1;
  u64 n1 = g ? a1 : o1;
  u64 mn = g ? o1 : a1;
  u64 mx = (a2 > o2) ? a2 : o2;
  a2 = (mn > mx) ? mn : mx;
  a1 = n1;
}

// One DPP top-2 combine step. BC=true (bound_ctrl zero-fill) for row_shr steps:
// self-merge at row edges would duplicate a key into b2 (K1==K2 bug); zero keys
// merge as no-ops. bcast steps keep old on masked lanes (dead thereafter).
template <int CTRL, int RMASK, bool BC>
__device__ __forceinline__ void dpp_top2_step(u64& b1, u64& b2) {
  int a1hi = (int)(unsigned)(b1 >> 32), a1lo = (int)(unsigned)(b1 & 0xFFFFFFFFull);
  int a2hi = (int)(unsigned)(b2 >> 32), a2lo = (int)(unsigned)(b2 & 0xFFFFFFFFull);
  int o1hi = __builtin_amdgcn_update_dpp(a1hi, a1hi, CTRL, RMASK, 0xF, BC);
  int o1lo = __builtin_amdgcn_update_dpp(a1lo, a1lo, CTRL, RMASK, 0xF, BC);
  int o2hi = __builtin_amdgcn_update_dpp(a2hi, a2hi, CTRL, RMASK, 0xF, BC);
  int o2lo = __builtin_amdgcn_update_dpp(a2lo, a2lo, CTRL, RMASK, 0xF, BC);
  top2_merge(b1, b2, mk64((unsigned)o1hi, (unsigned)o1lo),
             mk64((unsigned)o2hi, (unsigned)o2lo));
}

// ---------------- FPS with exact top-2 speculation --------------------------
// R2-proven skeleton (256 thr, 16 pts/lane, 1 barrier/round, parity dbuf).
// Per round: apply 1-2 pending winners (fused min, exact-assoc) + u64 top-2
// scan -> DPP top-2 butterfly -> lane63 writes pair -> barrier -> 3 merges ->
// K1 = next sample. Speculation: if d2(K2.pt, K1.pt) >= K2.dist then K2's key
// survives K1's update and every other key only shrinks (all ties resolved by
// key uniqueness) -> sample n+1 = K2 EXACTLY, no second reduce round.
__global__ __launch_bounds__(256) void fps_kernel(const float* __restrict__ pos,
                                                  int* __restrict__ idx_out) {
  const int b = blockIdx.x;
  const int t = threadIdx.x;
  __shared__ float4 s_pos4[NPER];                 // 64 KB
  __shared__ __align__(16) u64 s_red[2][8];       // [par][wave*2 + {b1,b2}]
  const float* pb = pos + (size_t)b * NPER * 3;
  for (int i = t; i < NPER; i += 256)
    s_pos4[i] = make_float4(pb[i * 3], pb[i * 3 + 1], pb[i * 3 + 2], 0.f);
  if (t == 0) idx_out[b * MS] = 0;
  __syncthreads();

  float px[16], py[16], pz[16], dist[16];
  unsigned lo16[16];
#pragma unroll
  for (int j = 0; j < 16; ++j) {
    float4 p = s_pos4[t + j * 256];
    px[j] = p.x; py[j] = p.y; pz[j] = p.z;
    dist[j] = __builtin_inff();
    lo16[j] = ~(unsigned)(t + j * 256);           // key low word: ~idx
  }
  const int w = t >> 6, lane = t & 63;
  float wxa[2], wya[2], wza[2];
  wxa[0] = s_pos4[0].x; wya[0] = s_pos4[0].y; wza[0] = s_pos4[0].z;
  int npend = 1, nout = 1, rnd = 0;

  while (nout < MS) {
    u64 b1 = 0, b2 = 0;
    if (npend == 2) {
#pragma unroll
      for (int j = 0; j < 16; ++j) {
        float nd = dist[j];
        nd = fminf(nd, d2_exact(px[j], py[j], pz[j], wxa[0], wya[0], wza[0]));
        nd = fminf(nd, d2_exact(px[j], py[j], pz[j], wxa[1], wya[1], wza[1]));
        dist[j] = nd;
        u64 kj = mk64(__float_as_uint(nd), lo16[j]);
        bool g = kj > b1;
        u64 b2c = g ? b1 : kj;
        b1 = g ? kj : b1;
        b2 = (b2c > b2) ? b2c : b2;
      }
    } else {
#pragma unroll
      for (int j = 0; j < 16; ++j) {
        float nd = dist[j];
        nd = fminf(nd, d2_exact(px[j], py[j], pz[j], wxa[0], wya[0], wza[0]));
        dist[j] = nd;
        u64 kj = mk64(__float_as_uint(nd), lo16[j]);
        bool g = kj > b1;
        u64 b2c = g ? b1 : kj;
        b1 = g ? kj : b1;
        b2 = (b2c > b2) ? b2c : b2;
      }
    }
    dpp_top2_step<0x111, 0xF, true>(b1, b2);   // row_shr:1 (zero-fill)
    dpp_top2_step<0x112, 0xF, true>(b1, b2);   // row_shr:2
    dpp_top2_step<0x114, 0xF, true>(b1, b2);   // row_shr:4
    dpp_top2_step<0x118, 0xF, true>(b1, b2);   // row_shr:8 -> lane15/row top2
    dpp_top2_step<0x142, 0xA, false>(b1, b2);  // row_bcast15 -> lane31/63
    dpp_top2_step<0x143, 0xC, false>(b1, b2);  // row_bcast31 -> lane63 = wave top2
    const int par = rnd & 1;
    if (lane == 63) { s_red[par][2 * w] = b1; s_red[par][2 * w + 1] = b2; }
    __syncthreads();
    ulonglong2 q0 = *(const ulonglong2*)&s_red[par][0];
    ulonglong2 q1 = *(const ulonglong2*)&s_red[par][2];
    ulonglong2 q2 = *(const ulonglong2*)&s_red[par][4];
    ulonglong2 q3 = *(const ulonglong2*)&s_red[par][6];
    u64 K1 = q0.x, K2 = q0.y;
    top2_merge(K1, K2, q1.x, q1.y);
    top2_merge(K1, K2, q2.x, q2.y);
    top2_merge(K1, K2, q3.x, q3.y);
    const unsigned i1 = ~(unsigned)(K1 & 0xFFFFFFFFull);
    const unsigned i2 = ~(unsigned)(K2 & 0xFFFFFFFFull);
    float4 wp1 = s_pos4[i1];                    // broadcast reads, overlap
    float4 wp2 = s_pos4[i2];
    float sd = d2_exact(wp2.x, wp2.y, wp2.z, wp1.x, wp1.y, wp1.z);
    float k2d = __uint_as_float((unsigned)(K2 >> 32));
    const bool spec = (sd >= k2d) && (nout <= MS - 2);  // uniform
    if (t == 0) {
      idx_out[b * MS + nout] = (int)i1;
      if (spec) idx_out[b * MS + nout + 1] = (int)i2;
    }
    wxa[0] = wp1.x; wya[0] = wp1.y; wza[0] = wp1.z;
    wxa[1] = wp2.x; wya[1] = wp2.y; wza[1] = wp2.z;
    npend = spec ? 2 : 1;
    nout += spec ? 2 : 1;
    rnd++;
  }
}

// ---- radius(top-64) + MFMA-bf16 MLP + masked neighbor max (R3, proven) ----
__global__ __launch_bounds__(512, 4) void radconv_kernel(
    const float* __restrict__ x, const float* __restrict__ pos,
    const int* __restrict__ idx,
    const float* __restrict__ W1, const float* __restrict__ B1,
    const float* __restrict__ W2, const float* __restrict__ B2,
    const float* __restrict__ W3, const float* __restrict__ B3,
    float* __restrict__ out) {
  const int t = threadIdx.x;
  const int g = blockIdx.x >> 9;          // graph
  const int qpair = blockIdx.x & 511;     // 512 blocks/graph * 2 queries
  const float* pb = pos + (size_t)g * NPER * 3;
  const float* xb = x + (size_t)g * NPER * CIN;

  __shared__ int s_cnt[2];
  __shared__ float s_ctr[2][4];
  __shared__ __align__(16) unsigned long long s_list[2][LCAP];  // 6 KB
  __shared__ int s_nbr[2][64];
  __shared__ __align__(16) unsigned short sFeat[2][64 * 104];   // 26 KB (reused as red)
  __shared__ __align__(16) unsigned short sW1[64 * 104];        // 13 KB  [col][k<=96pad]
  __shared__ __align__(16) unsigned short sW2[64 * 72];         // 9 KB   [col][k=64+pad]
  __shared__ __align__(16) unsigned short sW3[128 * 72];        // 18 KB

  if (t < 2) s_cnt[t] = 0;
  const int q0 = g * MS + qpair * 2;
  const int qiA = idx[q0], qiB = idx[q0 + 1];
  const float cAx = pb[qiA * 3], cAy = pb[qiA * 3 + 1], cAz = pb[qiA * 3 + 2];
  const float cBx = pb[qiB * 3], cBy = pb[qiB * 3 + 1], cBz = pb[qiB * 3 + 2];
  if (t == 0) { s_ctr[0][0] = cAx; s_ctr[0][1] = cAy; s_ctr[0][2] = cAz; }
  if (t == 1) { s_ctr[1][0] = cBx; s_ctr[1][1] = cBy; s_ctr[1][2] = cBz; }
  __syncthreads();  // B1: s_cnt zeroed

  // ---- search: 8 pts/thread, both queries --------------------------------
  {
    float pp[24];
    const float4* pv = (const float4*)(pb + (size_t)t * 24);
#pragma unroll
    for (int r = 0; r < 6; ++r) {
      float4 v = pv[r];
      pp[r * 4 + 0] = v.x; pp[r * 4 + 1] = v.y;
      pp[r * 4 + 2] = v.z; pp[r * 4 + 3] = v.w;
    }
#pragma unroll
    for (int jj = 0; jj < 8; ++jj) {
      const int j = t * 8 + jj;
      const float X = pp[jj * 3], Y = pp[jj * 3 + 1], Z = pp[jj * 3 + 2];
      float dA = d2_exact(X, Y, Z, cAx, cAy, cAz);
      if (dA <= 0.04f) {  // f32(0.04) == JAX's R*R
        int p = atomicAdd(&s_cnt[0], 1);
        if (p < LCAP)
          s_list[0][p] = ((unsigned long long)__float_as_uint(dA) << 32) | (unsigned)j;
      }
      float dB = d2_exact(X, Y, Z, cBx, cBy, cBz);
      if (dB <= 0.04f) {
        int p = atomicAdd(&s_cnt[1], 1);
        if (p < LCAP)
          s_list[1][p] = ((unsigned long long)__float_as_uint(dB) << 32) | (unsigned)j;
      }
    }
  }
  // ---- stage weights (bf16, transposed) — independent of search ----------
  for (int ee = t; ee < 64 * 64; ee += 512) {           // zero W1 k-pad 67..103
    int c = ee >> 6, kk = 67 + (ee & 63);
    if (kk < 104) sW1[c * 104 + kk] = 0;
  }
  for (int e = t; e < 67 * 64; e += 512) {              // W1t[c][k] = W1[k][c]
    int k = e >> 6, c = e & 63;
    sW1[c * 104 + k] = f2bf(W1[e]);
  }
  for (int e = t; e < 64 * 64; e += 512) {
    int k = e >> 6, c = e & 63;
    sW2[c * 72 + k] = f2bf(W2[e]);
  }
  for (int e = t; e < 64 * 128; e += 512) {
    int k = e >> 7, c = e & 127;
    sW3[c * 72 + k] = f2bf(W3[e]);
  }
  __syncthreads();  // B2: lists + weights ready

  const int w = t >> 6, lane = t & 63;
  const int c0 = min(min(s_cnt[0], LCAP), 64);
  const int c1 = min(min(s_cnt[1], LCAP), 64);

  // ---- exact top-64 by (d2, idx) via rank; 4 waves per query -------------
  {
    const int rq = w >> 2;
    const int nsurv = min(s_cnt[rq], LCAP);
    for (int e = (w & 3) * 64 + lane; e < nsurv; e += 256) {
      unsigned long long mykey = s_list[rq][e];
      int rank = 0;
      int o = 0;
      for (; o + 8 <= nsurv; o += 8) {
        unsigned long long k0 = s_list[rq][o + 0], k1 = s_list[rq][o + 1];
        unsigned long long k2 = s_list[rq][o + 2], k3 = s_list[rq][o + 3];
        unsigned long long k4 = s_list[rq][o + 4], k5 = s_list[rq][o + 5];
        unsigned long long k6 = s_list[rq][o + 6], k7 = s_list[rq][o + 7];
        rank += (k0 < mykey) + (k1 < mykey) + (k2 < mykey) + (k3 < mykey) +
                (k4 < mykey) + (k5 < mykey) + (k6 < mykey) + (k7 < mykey);
      }
      for (; o < nsurv; ++o) rank += (s_list[rq][o] < mykey) ? 1 : 0;
      if (rank < 64) s_nbr[rq][rank] = (int)(mykey & 0xFFFFFFFFull);
    }
  }
  __syncthreads();  // B3: nbr lists ready

  // ---- gather feat rows: [x_j bf16 (64) | rel (3) | 0 pad ... 96) --------
  {
    const int slot = t >> 2, part = t & 3;   // 128 slots x 4 parts
    const int gq = slot >> 6, s = slot & 63;
    const int cq = gq ? c1 : c0;
    unsigned short* frow = &sFeat[gq][s * 104];
    uint4 z; z.x = z.y = z.z = z.w = 0u;
    if (s < cq) {
      const int j = s_nbr[gq][s];
      const float4* xr = (const float4*)(xb + (size_t)j * CIN + part * 16);
      float4 v0 = xr[0], v1 = xr[1], v2 = xr[2], v3 = xr[3];
      uint4 w0, w1;
      w0.x = f2bf(v0.x) | ((unsigned)f2bf(v0.y) << 16);
      w0.y = f2bf(v0.z) | ((unsigned)f2bf(v0.w) << 16);
      w0.z = f2bf(v1.x) | ((unsigned)f2bf(v1.y) << 16);
      w0.w = f2bf(v1.z) | ((unsigned)f2bf(v1.w) << 16);
      w1.x = f2bf(v2.x) | ((unsigned)f2bf(v2.y) << 16);
      w1.y = f2bf(v2.z) | ((unsigned)f2bf(v2.w) << 16);
      w1.z = f2bf(v3.x) | ((unsigned)f2bf(v3.y) << 16);
      w1.w = f2bf(v3.z) | ((unsigned)f2bf(v3.w) << 16);
      *(uint4*)(frow + part * 16) = w0;
      *(uint4*)(frow + part * 16 + 8) = w1;
      uint4 rz = z;
      if (part == 0) {
        const float cx = gq ? cBx : cAx, cy = gq ? cBy : cAy, cz = gq ? cBz : cAz;
        rz.x = f2bf(pb[j * 3] - cx) | ((unsigned)f2bf(pb[j * 3 + 1] - cy) << 16);
        rz.y = (unsigned)f2bf(pb[j * 3 + 2] - cz);
      }
      *(uint4*)(frow + 64 + part * 8) = rz;
    } else {
      *(uint4*)(frow + part * 16) = z;
      *(uint4*)(frow + part * 16 + 8) = z;
      *(uint4*)(frow + 64 + part * 8) = z;
    }
  }
  __syncthreads();  // B4: feat ready

  // ---- MFMA MLP: wave -> (query qq2, row tile mt) ------------------------
  const int qq2 = w >> 2;
  const int mt = w & 3;
  const int lo = lane & 15, hi = lane >> 4;
  unsigned short* F = &sFeat[qq2][0];
  const int arow = (16 * mt + lo) * 104;
  const int hrow = (16 * mt + hi * 4) * 104;

  {  // layer 1: K=96 (3 steps), N=64
    f32x4 acc[4];
#pragma unroll
    for (int n = 0; n < 4; ++n) {
      float bb = B1[n * 16 + lo];
      acc[n] = (f32x4){bb, bb, bb, bb};
    }
    s16x8 a0 = *(const s16x8*)(F + arow + 0 + hi * 8);
    s16x8 a1 = *(const s16x8*)(F + arow + 32 + hi * 8);
    s16x8 a2 = *(const s16x8*)(F + arow + 64 + hi * 8);
#pragma unroll
    for (int n = 0; n < 4; ++n) {
      const unsigned short* Bp = &sW1[(n * 16 + lo) * 104 + hi * 8];
      s16x8 b0 = *(const s16x8*)(Bp);
      s16x8 b1 = *(const s16x8*)(Bp + 32);
      s16x8 b2 = *(const s16x8*)(Bp + 64);
      acc[n] = __builtin_amdgcn_mfma_f32_16x16x32_bf16(a0, b0, acc[n], 0, 0, 0);
      acc[n] = __builtin_amdgcn_mfma_f32_16x16x32_bf16(a1, b1, acc[n], 0, 0, 0);
      acc[n] = __builtin_amdgcn_mfma_f32_16x16x32_bf16(a2, b2, acc[n], 0, 0, 0);
    }
#pragma unroll
    for (int n = 0; n < 4; ++n)
#pragma unroll
      for (int r = 0; r < 4; ++r)
        F[hrow + r * 104 + n * 16 + lo] = f2bf(fmaxf(acc[n][r], 0.f));
  }
  {  // layer 2: K=64 (2 steps), N=64
    f32x4 acc[4];
#pragma unroll
    for (int n = 0; n < 4; ++n) {
      float bb = B2[n * 16 + lo];
      acc[n] = (f32x4){bb, bb, bb, bb};
    }
    s16x8 a0 = *(const s16x8*)(F + arow + 0 + hi * 8);
    s16x8 a1 = *(const s16x8*)(F + arow + 32 + hi * 8);
#pragma unroll
    for (int n = 0; n < 4; ++n) {
      const unsigned short* Bp = &sW2[(n * 16 + lo) * 72 + hi * 8];
      s16x8 b0 = *(const s16x8*)(Bp);
      s16x8 b1 = *(const s16x8*)(Bp + 32);
      acc[n] = __builtin_amdgcn_mfma_f32_16x16x32_bf16(a0, b0, acc[n], 0, 0, 0);
      acc[n] = __builtin_amdgcn_mfma_f32_16x16x32_bf16(a1, b1, acc[n], 0, 0, 0);
    }
#pragma unroll
    for (int n = 0; n < 4; ++n)
#pragma unroll
      for (int r = 0; r < 4; ++r)
        F[hrow + r * 104 + n * 16 + lo] = f2bf(fmaxf(acc[n][r], 0.f));
  }
  float pm[8];
  {  // layer 3: K=64 (2 steps), N=128, fused masked row-max
    const int cq = qq2 ? c1 : c0;
    f32x4 acc[8];
#pragma unroll
    for (int n = 0; n < 8; ++n) {
      float bb = B3[n * 16 + lo];
      acc[n] = (f32x4){bb, bb, bb, bb};
    }
    s16x8 a0 = *(const s16x8*)(F + arow + 0 + hi * 8);
    s16x8 a1 = *(const s16x8*)(F + arow + 32 + hi * 8);
#pragma unroll
    for (int n = 0; n < 8; ++n) {
      const unsigned short* Bp = &sW3[(n * 16 + lo) * 72 + hi * 8];
      s16x8 b0 = *(const s16x8*)(Bp);
      s16x8 b1 = *(const s16x8*)(Bp + 32);
      acc[n] = __builtin_amdgcn_mfma_f32_16x16x32_bf16(a0, b0, acc[n], 0, 0, 0);
      acc[n] = __builtin_amdgcn_mfma_f32_16x16x32_bf16(a1, b1, acc[n], 0, 0, 0);
    }
#pragma unroll
    for (int n = 0; n < 8; ++n) {
      float v = -1e30f;
#pragma unroll
      for (int r = 0; r < 4; ++r) {
        int row = 16 * mt + hi * 4 + r;
        if (row < cq) v = fmaxf(v, fmaxf(acc[n][r], 0.f));
      }
      pm[n] = v;
    }
  }
  __syncthreads();  // B5: all sFeat reads done -> reuse as reduction buffer

  float* red = (float*)&sFeat[0][0];  // [2][128][17] floats
#pragma unroll
  for (int n = 0; n < 8; ++n)
    red[((qq2 * 128) + n * 16 + lo) * 17 + mt * 4 + hi] = pm[n];
  __syncthreads();  // B6

  if (t < 256) {
    const int gq = t >> 7, cc = t & 127;
    const float* rp = red + (gq * 128 + cc) * 17;
    float v = rp[0];
#pragma unroll
    for (int p = 1; p < 16; ++p) v = fmaxf(v, rp[p]);
    out[(size_t)(q0 + gq) * 128 + cc] = v;
  }
  if (t == 256 || t == 257) {
    const int gq = t - 256;
    const int qrow = q0 + gq;
    out[524288 + qrow * 3 + 0] = s_ctr[gq][0];
    out[524288 + qrow * 3 + 1] = s_ctr[gq][1];
    out[524288 + qrow * 3 + 2] = s_ctr[gq][2];
    out[536576 + qrow] = (float)g;
  }
}

extern "C" void kernel_launch(void* const* d_in, const int* in_sizes, int n_in,
                              void* d_out, int out_size, void* d_ws, size_t ws_size,
                              hipStream_t stream) {
  const float* x   = (const float*)d_in[0];
  const float* pos = (const float*)d_in[1];
  const float* W1  = (const float*)d_in[3];
  const float* B1  = (const float*)d_in[4];
  const float* W2  = (const float*)d_in[5];
  const float* B2  = (const float*)d_in[6];
  const float* W3  = (const float*)d_in[7];
  const float* B3  = (const float*)d_in[8];
  float* out = (float*)d_out;
  int* idx = (int*)d_ws;  // 4096 ints

  fps_kernel<<<4, 256, 0, stream>>>(pos, idx);
  radconv_kernel<<<2048, 512, 0, stream>>>(x, pos, idx, W1, B1, W2, B2, W3, B3, out);
}

// Round 12
// 652.174 us; speedup vs baseline: 1.2607x; 1.2607x over previous
//
#include <hip/hip_runtime.h>

#define NPER 4096
#define MS   1024
#define CIN  64
#define LCAP 384

typedef float  f32x4 __attribute__((ext_vector_type(4)));
typedef short  s16x8 __attribute__((ext_vector_type(8)));

// Exact d2 matching the numpy/XLA reference: per-component sub, rounded square,
// left-assoc sum. _rn forbids fma contraction -> bit-exact ball/argmax picks.
__device__ __forceinline__ float d2_exact(float ax, float ay, float az,
                                          float bx, float by, float bz) {
  float dx = __fsub_rn(ax, bx);
  float dy = __fsub_rn(ay, by);
  float dz = __fsub_rn(az, bz);
  return __fadd_rn(__fadd_rn(__fmul_rn(dx, dx), __fmul_rn(dy, dy)), __fmul_rn(dz, dz));
}

// f32 -> bf16 (RNE) bit pattern
__device__ __forceinline__ unsigned short f2bf(float f) {
  unsigned b = __float_as_uint(f);
  return (unsigned short)((b + 0x7FFFu + ((b >> 16) & 1u)) >> 16);
}

template <int CTRL, int RMASK>
__device__ __forceinline__ unsigned long long dpp_max_step(unsigned long long k) {
  int hi = (int)(unsigned)(k >> 32);
  int lo = (int)(unsigned)(k & 0xFFFFFFFFull);
  int thi = __builtin_amdgcn_update_dpp(hi, hi, CTRL, RMASK, 0xF, false);
  int tlo = __builtin_amdgcn_update_dpp(lo, lo, CTRL, RMASK, 0xF, false);
  unsigned long long t =
      ((unsigned long long)(unsigned)thi << 32) | (unsigned)tlo;
  return t > k ? t : k;
}

__device__ __forceinline__ unsigned long long u64max(unsigned long long a,
                                                    unsigned long long b) {
  return a > b ? a : b;
}

// ---------------- FPS: one block per graph, 256 threads, 16 pts/thread ------
// R2-proven kernel, verbatim (measured 597 us). Per iter: register d2+min+best
// (linear strict-> chain) -> DPP butterfly (lane63 = wave max) -> lane63 writes
// key -> ONE barrier -> all threads redundantly reduce the 4 wave keys
// (broadcast b128 reads) -> winner coords via one b128 read. s_red is
// parity-double-buffered so no second barrier is needed.
__global__ __launch_bounds__(256) void fps_kernel(const float* __restrict__ pos,
                                                  int* __restrict__ idx_out) {
  const int b = blockIdx.x;
  const int t = threadIdx.x;
  __shared__ float4 s_pos4[NPER];                       // 64 KB
  __shared__ __align__(16) unsigned long long s_red[2][4];
  const float* pb = pos + (size_t)b * NPER * 3;
  for (int i = t; i < NPER; i += 256)
    s_pos4[i] = make_float4(pb[i * 3], pb[i * 3 + 1], pb[i * 3 + 2], 0.f);
  if (t == 0) idx_out[b * MS] = 0;
  __syncthreads();

  float px[16], py[16], pz[16], dist[16];
#pragma unroll
  for (int j = 0; j < 16; ++j) {
    float4 p = s_pos4[t + j * 256];
    px[j] = p.x; py[j] = p.y; pz[j] = p.z;
    dist[j] = __builtin_inff();
  }
  const int w = t >> 6;
  const int lane = t & 63;

  float lx = s_pos4[0].x, ly = s_pos4[0].y, lz = s_pos4[0].z;

  for (int m = 1; m < MS; ++m) {
    float bd = -1.0f;
    int bi = 0;
#pragma unroll
    for (int j = 0; j < 16; ++j) {
      float d2 = d2_exact(px[j], py[j], pz[j], lx, ly, lz);
      float nd = fminf(dist[j], d2);
      dist[j] = nd;
      if (nd > bd) { bd = nd; bi = t + j * 256; }  // strict >: lowest idx on tie
    }
    // pack (dist_bits << 32) | ~idx : u64 max == max dist, tie -> min idx
    unsigned long long k =
        ((unsigned long long)__float_as_uint(bd) << 32) | (unsigned)(~bi);
    k = dpp_max_step<0x111, 0xF>(k);  // row_shr:1
    k = dpp_max_step<0x112, 0xF>(k);  // row_shr:2
    k = dpp_max_step<0x114, 0xF>(k);  // row_shr:4
    k = dpp_max_step<0x118, 0xF>(k);  // row_shr:8
    k = dpp_max_step<0x142, 0xA>(k);  // row_bcast15
    k = dpp_max_step<0x143, 0xC>(k);  // row_bcast31 -> lane63 = wave max
    const int par = m & 1;
    if (lane == 63) s_red[par][w] = k;
    __syncthreads();
    ulonglong2 ab = *reinterpret_cast<const ulonglong2*>(&s_red[par][0]);
    ulonglong2 cd = *reinterpret_cast<const ulonglong2*>(&s_red[par][2]);
    unsigned long long kb = u64max(u64max(ab.x, ab.y), u64max(cd.x, cd.y));
    const int nx = (int)(~(unsigned)(kb & 0xFFFFFFFFull));
    if (t == 0) idx_out[b * MS + m] = nx;
    float4 wp = s_pos4[nx];  // broadcast read
    lx = wp.x; ly = wp.y; lz = wp.z;
  }
}

// ---- radius(top-64) + MFMA-bf16 MLP + masked neighbor max (R3, proven) ----
__global__ __launch_bounds__(512, 4) void radconv_kernel(
    const float* __restrict__ x, const float* __restrict__ pos,
    const int* __restrict__ idx,
    const float* __restrict__ W1, const float* __restrict__ B1,
    const float* __restrict__ W2, const float* __restrict__ B2,
    const float* __restrict__ W3, const float* __restrict__ B3,
    float* __restrict__ out) {
  const int t = threadIdx.x;
  const int g = blockIdx.x >> 9;          // graph
  const int qpair = blockIdx.x & 511;     // 512 blocks/graph * 2 queries
  const float* pb = pos + (size_t)g * NPER * 3;
  const float* xb = x + (size_t)g * NPER * CIN;

  __shared__ int s_cnt[2];
  __shared__ float s_ctr[2][4];
  __shared__ __align__(16) unsigned long long s_list[2][LCAP];  // 6 KB
  __shared__ int s_nbr[2][64];
  __shared__ __align__(16) unsigned short sFeat[2][64 * 104];   // 26 KB (reused as red)
  __shared__ __align__(16) unsigned short sW1[64 * 104];        // 13 KB  [col][k<=96pad]
  __shared__ __align__(16) unsigned short sW2[64 * 72];         // 9 KB   [col][k=64+pad]
  __shared__ __align__(16) unsigned short sW3[128 * 72];        // 18 KB

  if (t < 2) s_cnt[t] = 0;
  const int q0 = g * MS + qpair * 2;
  const int qiA = idx[q0], qiB = idx[q0 + 1];
  const float cAx = pb[qiA * 3], cAy = pb[qiA * 3 + 1], cAz = pb[qiA * 3 + 2];
  const float cBx = pb[qiB * 3], cBy = pb[qiB * 3 + 1], cBz = pb[qiB * 3 + 2];
  if (t == 0) { s_ctr[0][0] = cAx; s_ctr[0][1] = cAy; s_ctr[0][2] = cAz; }
  if (t == 1) { s_ctr[1][0] = cBx; s_ctr[1][1] = cBy; s_ctr[1][2] = cBz; }
  __syncthreads();  // B1: s_cnt zeroed

  // ---- search: 8 pts/thread, both queries --------------------------------
  {
    float pp[24];
    const float4* pv = (const float4*)(pb + (size_t)t * 24);
#pragma unroll
    for (int r = 0; r < 6; ++r) {
      float4 v = pv[r];
      pp[r * 4 + 0] = v.x; pp[r * 4 + 1] = v.y;
      pp[r * 4 + 2] = v.z; pp[r * 4 + 3] = v.w;
    }
#pragma unroll
    for (int jj = 0; jj < 8; ++jj) {
      const int j = t * 8 + jj;
      const float X = pp[jj * 3], Y = pp[jj * 3 + 1], Z = pp[jj * 3 + 2];
      float dA = d2_exact(X, Y, Z, cAx, cAy, cAz);
      if (dA <= 0.04f) {  // f32(0.04) == JAX's R*R
        int p = atomicAdd(&s_cnt[0], 1);
        if (p < LCAP)
          s_list[0][p] = ((unsigned long long)__float_as_uint(dA) << 32) | (unsigned)j;
      }
      float dB = d2_exact(X, Y, Z, cBx, cBy, cBz);
      if (dB <= 0.04f) {
        int p = atomicAdd(&s_cnt[1], 1);
        if (p < LCAP)
          s_list[1][p] = ((unsigned long long)__float_as_uint(dB) << 32) | (unsigned)j;
      }
    }
  }
  // ---- stage weights (bf16, transposed) — independent of search ----------
  for (int ee = t; ee < 64 * 64; ee += 512) {           // zero W1 k-pad 67..103
    int c = ee >> 6, kk = 67 + (ee & 63);
    if (kk < 104) sW1[c * 104 + kk] = 0;
  }
  for (int e = t; e < 67 * 64; e += 512) {              // W1t[c][k] = W1[k][c]
    int k = e >> 6, c = e & 63;
    sW1[c * 104 + k] = f2bf(W1[e]);
  }
  for (int e = t; e < 64 * 64; e += 512) {
    int k = e >> 6, c = e & 63;
    sW2[c * 72 + k] = f2bf(W2[e]);
  }
  for (int e = t; e < 64 * 128; e += 512) {
    int k = e >> 7, c = e & 127;
    sW3[c * 72 + k] = f2bf(W3[e]);
  }
  __syncthreads();  // B2: lists + weights ready

  const int w = t >> 6, lane = t & 63;
  const int c0 = min(min(s_cnt[0], LCAP), 64);
  const int c1 = min(min(s_cnt[1], LCAP), 64);

  // ---- exact top-64 by (d2, idx) via rank; 4 waves per query -------------
  {
    const int rq = w >> 2;
    const int nsurv = min(s_cnt[rq], LCAP);
    for (int e = (w & 3) * 64 + lane; e < nsurv; e += 256) {
      unsigned long long mykey = s_list[rq][e];
      int rank = 0;
      int o = 0;
      for (; o + 8 <= nsurv; o += 8) {
        unsigned long long k0 = s_list[rq][o + 0], k1 = s_list[rq][o + 1];
        unsigned long long k2 = s_list[rq][o + 2], k3 = s_list[rq][o + 3];
        unsigned long long k4 = s_list[rq][o + 4], k5 = s_list[rq][o + 5];
        unsigned long long k6 = s_list[rq][o + 6], k7 = s_list[rq][o + 7];
        rank += (k0 < mykey) + (k1 < mykey) + (k2 < mykey) + (k3 < mykey) +
                (k4 < mykey) + (k5 < mykey) + (k6 < mykey) + (k7 < mykey);
      }
      for (; o < nsurv; ++o) rank += (s_list[rq][o] < mykey) ? 1 : 0;
      if (rank < 64) s_nbr[rq][rank] = (int)(mykey & 0xFFFFFFFFull);
    }
  }
  __syncthreads();  // B3: nbr lists ready

  // ---- gather feat rows: [x_j bf16 (64) | rel (3) | 0 pad ... 96) --------
  {
    const int slot = t >> 2, part = t & 3;   // 128 slots x 4 parts
    const int gq = slot >> 6, s = slot & 63;
    const int cq = gq ? c1 : c0;
    unsigned short* frow = &sFeat[gq][s * 104];
    uint4 z; z.x = z.y = z.z = z.w = 0u;
    if (s < cq) {
      const int j = s_nbr[gq][s];
      const float4* xr = (const float4*)(xb + (size_t)j * CIN + part * 16);
      float4 v0 = xr[0], v1 = xr[1], v2 = xr[2], v3 = xr[3];
      uint4 w0, w1;
      w0.x = f2bf(v0.x) | ((unsigned)f2bf(v0.y) << 16);
      w0.y = f2bf(v0.z) | ((unsigned)f2bf(v0.w) << 16);
      w0.z = f2bf(v1.x) | ((unsigned)f2bf(v1.y) << 16);
      w0.w = f2bf(v1.z) | ((unsigned)f2bf(v1.w) << 16);
      w1.x = f2bf(v2.x) | ((unsigned)f2bf(v2.y) << 16);
      w1.y = f2bf(v2.z) | ((unsigned)f2bf(v2.w) << 16);
      w1.z = f2bf(v3.x) | ((unsigned)f2bf(v3.y) << 16);
      w1.w = f2bf(v3.z) | ((unsigned)f2bf(v3.w) << 16);
      *(uint4*)(frow + part * 16) = w0;
      *(uint4*)(frow + part * 16 + 8) = w1;
      uint4 rz = z;
      if (part == 0) {
        const float cx = gq ? cBx : cAx, cy = gq ? cBy : cAy, cz = gq ? cBz : cAz;
        rz.x = f2bf(pb[j * 3] - cx) | ((unsigned)f2bf(pb[j * 3 + 1] - cy) << 16);
        rz.y = (unsigned)f2bf(pb[j * 3 + 2] - cz);
      }
      *(uint4*)(frow + 64 + part * 8) = rz;
    } else {
      *(uint4*)(frow + part * 16) = z;
      *(uint4*)(frow + part * 16 + 8) = z;
      *(uint4*)(frow + 64 + part * 8) = z;
    }
  }
  __syncthreads();  // B4: feat ready

  // ---- MFMA MLP: wave -> (query qq2, row tile mt) ------------------------
  const int qq2 = w >> 2;
  const int mt = w & 3;
  const int lo = lane & 15, hi = lane >> 4;
  unsigned short* F = &sFeat[qq2][0];
  const int arow = (16 * mt + lo) * 104;
  const int hrow = (16 * mt + hi * 4) * 104;

  {  // layer 1: K=96 (3 steps), N=64
    f32x4 acc[4];
#pragma unroll
    for (int n = 0; n < 4; ++n) {
      float bb = B1[n * 16 + lo];
      acc[n] = (f32x4){bb, bb, bb, bb};
    }
    s16x8 a0 = *(const s16x8*)(F + arow + 0 + hi * 8);
    s16x8 a1 = *(const s16x8*)(F + arow + 32 + hi * 8);
    s16x8 a2 = *(const s16x8*)(F + arow + 64 + hi * 8);
#pragma unroll
    for (int n = 0; n < 4; ++n) {
      const unsigned short* Bp = &sW1[(n * 16 + lo) * 104 + hi * 8];
      s16x8 b0 = *(const s16x8*)(Bp);
      s16x8 b1 = *(const s16x8*)(Bp + 32);
      s16x8 b2 = *(const s16x8*)(Bp + 64);
      acc[n] = __builtin_amdgcn_mfma_f32_16x16x32_bf16(a0, b0, acc[n], 0, 0, 0);
      acc[n] = __builtin_amdgcn_mfma_f32_16x16x32_bf16(a1, b1, acc[n], 0, 0, 0);
      acc[n] = __builtin_amdgcn_mfma_f32_16x16x32_bf16(a2, b2, acc[n], 0, 0, 0);
    }
#pragma unroll
    for (int n = 0; n < 4; ++n)
#pragma unroll
      for (int r = 0; r < 4; ++r)
        F[hrow + r * 104 + n * 16 + lo] = f2bf(fmaxf(acc[n][r], 0.f));
  }
  {  // layer 2: K=64 (2 steps), N=64
    f32x4 acc[4];
#pragma unroll
    for (int n = 0; n < 4; ++n) {
      float bb = B2[n * 16 + lo];
      acc[n] = (f32x4){bb, bb, bb, bb};
    }
    s16x8 a0 = *(const s16x8*)(F + arow + 0 + hi * 8);
    s16x8 a1 = *(const s16x8*)(F + arow + 32 + hi * 8);
#pragma unroll
    for (int n = 0; n < 4; ++n) {
      const unsigned short* Bp = &sW2[(n * 16 + lo) * 72 + hi * 8];
      s16x8 b0 = *(const s16x8*)(Bp);
      s16x8 b1 = *(const s16x8*)(Bp + 32);
      acc[n] = __builtin_amdgcn_mfma_f32_16x16x32_bf16(a0, b0, acc[n], 0, 0, 0);
      acc[n] = __builtin_amdgcn_mfma_f32_16x16x32_bf16(a1, b1, acc[n], 0, 0, 0);
    }
#pragma unroll
    for (int n = 0; n < 4; ++n)
#pragma unroll
      for (int r = 0; r < 4; ++r)
        F[hrow + r * 104 + n * 16 + lo] = f2bf(fmaxf(acc[n][r], 0.f));
  }
  float pm[8];
  {  // layer 3: K=64 (2 steps), N=128, fused masked row-max
    const int cq = qq2 ? c1 : c0;
    f32x4 acc[8];
#pragma unroll
    for (int n = 0; n < 8; ++n) {
      float bb = B3[n * 16 + lo];
      acc[n] = (f32x4){bb, bb, bb, bb};
    }
    s16x8 a0 = *(const s16x8*)(F + arow + 0 + hi * 8);
    s16x8 a1 = *(const s16x8*)(F + arow + 32 + hi * 8);
#pragma unroll
    for (int n = 0; n < 8; ++n) {
      const unsigned short* Bp = &sW3[(n * 16 + lo) * 72 + hi * 8];
      s16x8 b0 = *(const s16x8*)(Bp);
      s16x8 b1 = *(const s16x8*)(Bp + 32);
      acc[n] = __builtin_amdgcn_mfma_f32_16x16x32_bf16(a0, b0, acc[n], 0, 0, 0);
      acc[n] = __builtin_amdgcn_mfma_f32_16x16x32_bf16(a1, b1, acc[n], 0, 0, 0);
    }
#pragma unroll
    for (int n = 0; n < 8; ++n) {
      float v = -1e30f;
#pragma unroll
      for (int r = 0; r < 4; ++r) {
        int row = 16 * mt + hi * 4 + r;
        if (row < cq) v = fmaxf(v, fmaxf(acc[n][r], 0.f));
      }
      pm[n] = v;
    }
  }
  __syncthreads();  // B5: all sFeat reads done -> reuse as reduction buffer

  float* red = (float*)&sFeat[0][0];  // [2][128][17] floats
#pragma unroll
  for (int n = 0; n < 8; ++n)
    red[((qq2 * 128) + n * 16 + lo) * 17 + mt * 4 + hi] = pm[n];
  __syncthreads();  // B6

  if (t < 256) {
    const int gq = t >> 7, cc = t & 127;
    const float* rp = red + (gq * 128 + cc) * 17;
    float v = rp[0];
#pragma unroll
    for (int p = 1; p < 16; ++p) v = fmaxf(v, rp[p]);
    out[(size_t)(q0 + gq) * 128 + cc] = v;
  }
  if (t == 256 || t == 257) {
    const int gq = t - 256;
    const int qrow = q0 + gq;
    out[524288 + qrow * 3 + 0] = s_ctr[gq][0];
    out[524288 + qrow * 3 + 1] = s_ctr[gq][1];
    out[524288 + qrow * 3 + 2] = s_ctr[gq][2];
    out[536576 + qrow] = (float)g;
  }
}

extern "C" void kernel_launch(void* const* d_in, const int* in_sizes, int n_in,
                              void* d_out, int out_size, void* d_ws, size_t ws_size,
                              hipStream_t stream) {
  const float* x   = (const float*)d_in[0];
  const float* pos = (const float*)d_in[1];
  const float* W1  = (const float*)d_in[3];
  const float* B1  = (const float*)d_in[4];
  const float* W2  = (const float*)d_in[5];
  const float* B2  = (const float*)d_in[6];
  const float* W3  = (const float*)d_in[7];
  const float* B3  = (const float*)d_in[8];
  float* out = (float*)d_out;
  int* idx = (int*)d_ws;  // 4096 ints

  fps_kernel<<<4, 256, 0, stream>>>(pos, idx);
  radconv_kernel<<<2048, 512, 0, stream>>>(x, pos, idx, W1, B1, W2, B2, W3, B3, out);
}